// Round 7
// baseline (476.323 us; speedup 1.0000x reference)
//
#include <hip/hip_runtime.h>
#include <math.h>

typedef __attribute__((ext_vector_type(8))) short short8v;   // 8 bf16 = 4 VGPRs
typedef __attribute__((ext_vector_type(4))) float float4v;   // MFMA acc

constexpr int Bsz = 8, Tn = 16, CINc = 6, Fc = 64, NCc = 10;
constexpr int PIX = 8192;                 // 8*32*32 pixels per timestep
constexpr float BN_EPS = 1e-3f;

// weight-fragment region offsets (in ushort elements)
constexpr int FR_L0X = 0;                 // 2 chunks  (K=54 padded to 64)
constexpr int FR_L0H = 16384;             // 18 chunks (K=576)
constexpr int FR_L1X = 163840;            // 18 chunks
constexpr int FR_L1H = 311296;            // 18 chunks
constexpr int FR_TOTAL = 458752;

__device__ __forceinline__ ushort f2bf(float f) {
    union { float f; unsigned u; } v; v.f = f;
    unsigned r = v.u + 0x7FFFu + ((v.u >> 16) & 1u);   // RNE
    return (ushort)(r >> 16);
}
__device__ __forceinline__ float bf2f(ushort u) {
    union { unsigned u; float f; } v; v.u = ((unsigned)u) << 16; return v.f;
}
__device__ __forceinline__ float hsig(float x) {
    return fminf(fmaxf(0.2f * x + 0.5f, 0.0f), 1.0f);
}

#define GLDS(srcp, dstp) \
    __builtin_amdgcn_global_load_lds((const __attribute__((address_space(1))) void*)(srcp), \
                                     (__attribute__((address_space(3))) void*)(dstp), 16, 0, 0)

// ---------------- prep: x -> bf16 [t][pix][6] ----------------
__global__ __launch_bounds__(256) void prep_x(const float* __restrict__ in,
                                              ushort* __restrict__ xb) {
    int o = blockIdx.x * 256 + threadIdx.x;        // 16*8192*6 = 786432
    if (o >= Tn * PIX * CINc) return;
    int t = o / (PIX * CINc);
    int rem = o - t * (PIX * CINc);
    int pix = rem / CINc, c = rem - pix * CINc;
    int b = pix >> 10, p = pix & 1023;
    xb[o] = f2bf(in[((b * Tn + t) * 1024 + p) * CINc + c]);
}

// ---------------- prep: weights -> grouped B-fragment layout ----------------
// region layout: [kc][nh][j(0..7)][lane(0..63)][e(0..7)]; frag's nt = (j>>1)*4 + nh*2 + (j&1)
// element: k = kc*32 + (lane>>4)*4 + (e&3) + 16*(e>>2); n = nt*16 + (lane&15)
__global__ __launch_bounds__(256) void prep_w(const float* __restrict__ W0x,
                                              const float* __restrict__ W0h,
                                              const float* __restrict__ W1x,
                                              const float* __restrict__ W1h,
                                              ushort* __restrict__ F) {
    int o = blockIdx.x * 256 + threadIdx.x;
    if (o >= FR_TOTAL) return;
    const float* W; int K; int base;
    if (o < FR_L0H)      { W = W0x; K = 54;  base = FR_L0X; }
    else if (o < FR_L1X) { W = W0h; K = 576; base = FR_L0H; }
    else if (o < FR_L1H) { W = W1x; K = 576; base = FR_L1X; }
    else                 { W = W1h; K = 576; base = FR_L1H; }
    int r = o - base;
    int e = r & 7, lane = (r >> 3) & 63, j = (r >> 9) & 7, nh = (r >> 12) & 1, kc = r >> 13;
    int nt = ((j >> 1) << 2) + nh * 2 + (j & 1);
    int k = kc * 32 + ((lane >> 4) * 4) + (e & 3) + 16 * (e >> 2);
    int n = nt * 16 + (lane & 15);
    F[o] = (k < K) ? f2bf(W[k * 256 + n]) : (ushort)0;
}

// ---------------- init ----------------
__global__ __launch_bounds__(256) void init_zero(float* c0, float* c1,
                                                 ushort* h0, ushort* h1,
                                                 ushort* h0b, ushort* h1b, float* out) {
    int i = blockIdx.x * 256 + threadIdx.x;
    if (i < PIX * Fc) { c0[i] = 0.f; c1[i] = 0.f; h0[i] = 0; h1[i] = 0; h0b[i] = 0; h1b[i] = 0; }
    if (i < Bsz * NCc) out[i] = 0.f;
}

// ---------------- dual-layer pipelined step (single barrier per chunk) ----------------
// Blocks 0..255:   layer-0 step t      (skip if t >= 16): z = conv(x_t,W0x)+conv(h0,W0h)+b0
// Blocks 256..511: layer-1 step t-1    (skip if t == 0):  z = conv(x1[t-1],W1x)+conv(h1,W1h)+b1
// Each block: 64 pixels x 128 gate-paired channels (nh half); register-local gate math.
// Pipeline: A dbuf in LDS (1 barrier/chunk); B glds issued at chunk top (full-body flight);
// A global->reg prefetch at distance 2.
__global__ __launch_bounds__(256) void step_dual(
    int t,
    const ushort* __restrict__ Xb,
    const ushort* __restrict__ Bf0X, const ushort* __restrict__ Bf0H,
    const float* __restrict__ b0,
    float* __restrict__ C0, const ushort* __restrict__ H0prev, ushort* __restrict__ H0cur,
    ushort* __restrict__ X1s,
    const float* __restrict__ g0, const float* __restrict__ be0,
    const float* __restrict__ mn0, const float* __restrict__ v0,
    const ushort* __restrict__ Bf1X, const ushort* __restrict__ Bf1H,
    const float* __restrict__ b1,
    float* __restrict__ C1, const ushort* __restrict__ H1prev, ushort* __restrict__ H1cur,
    ushort* __restrict__ H1s)
{
    const int layer = blockIdx.x >> 8;
    if (layer == 0) { if (t >= Tn) return; }
    else            { if (t == 0)  return; }

    __shared__ ushort As[2][2560];        // dbuf: 64 rows x 32k (+8 pad) = 80B rows
    __shared__ ushort Bs[2][4096];        // dbuf: 8KB B group

    const int tid = threadIdx.x;
    const int wid = tid >> 6, lane = tid & 63;
    const int bid = blockIdx.x & 255;
    const int bm = bid >> 1, nh = bid & 1;
    const int m0 = bm * 64;

    const int p_local = tid >> 2, kq = tid & 3;
    const int p_global = m0 + p_local;
    const int img = p_global >> 10, pp = p_global & 1023;
    const int py = pp >> 5, px = pp & 31;

    const int arow = (wid * 16 + (lane & 15)) * 80 + (lane >> 4) * 8;   // bytes
    const int awr  = p_local * 80 + kq * 16;                            // bytes

    // per-layer bindings
    const int t1 = t - 1;
    const ushort* __restrict__ Xt    = Xb + t * PIX * CINc;                  // layer 0
    const ushort* __restrict__ X1t1  = X1s + (size_t)t1 * (PIX * Fc);        // layer 1
    const ushort* __restrict__ Hprev = (layer == 0) ? H0prev : H1prev;
    ushort* __restrict__ Hcur        = (layer == 0) ? H0cur : H1cur;
    float* __restrict__ C            = (layer == 0) ? C0 : C1;
    const float* __restrict__ bias   = (layer == 0) ? b0 : b1;
    ushort* __restrict__ Seq         = (layer == 0) ? (X1s + (size_t)t * (PIX * Fc))
                                                    : (H1s + (size_t)t1 * (PIX * Fc));
    const int TOT = (layer == 0) ? 20 : 36;      // L0: 2 x-chunks + 18 h; L1: 18 + 18

    auto bptr = [&](int q) -> const ushort* {
        if (layer == 0)
            return (q < 2)  ? Bf0X + ((q * 2 + nh) << 12)
                            : Bf0H + (((q - 2) * 2 + nh) << 12);
        else
            return (q < 18) ? Bf1X + ((q * 2 + nh) << 12)
                            : Bf1H + (((q - 18) * 2 + nh) << 12);
    };
    auto stageB = [&](int q, int buf) {
        const ushort* g = bptr(q);
        GLDS(g + (tid << 3),         &Bs[buf][(wid) * 512]);
        GLDS(g + ((256 + tid) << 3), &Bs[buf][(4 + wid) * 512]);
    };
    auto gather64 = [&](const ushort* __restrict__ P, int kc) -> uint4 {
        uint4 av = make_uint4(0u, 0u, 0u, 0u);
        int tap = kc >> 1;
        int c0h = ((kc & 1) << 5) + (kq << 3);
        int dy = tap / 3 - 1, dx = tap % 3 - 1;
        int gy = py + dy, gx = px + dx;
        if ((unsigned)gy < 32u && (unsigned)gx < 32u)
            av = *(const uint4*)(P + (((img << 10) + gy * 32 + gx) << 6) + c0h);
        return av;
    };
    auto gatherA = [&](int q) -> uint4 {
        if (layer == 0) {
            if (q < 2) {                         // x path, Ch=6, K=54 pad 64
                union { ushort s[8]; uint4 u; } pk;
#pragma unroll
                for (int j = 0; j < 8; ++j) {
                    int kg = q * 32 + kq * 8 + j;
                    ushort v = 0;
                    if (kg < 54) {
                        int tap = kg / 6, c = kg - tap * 6;
                        int dy = tap / 3 - 1, dx = tap % 3 - 1;
                        int gy = py + dy, gx = px + dx;
                        if ((unsigned)gy < 32u && (unsigned)gx < 32u)
                            v = Xt[((img << 10) + gy * 32 + gx) * 6 + c];
                    }
                    pk.s[j] = v;
                }
                return pk.u;
            }
            return gather64(Hprev, q - 2);
        } else {
            return (q < 18) ? gather64(X1t1, q) : gather64(Hprev, q - 18);
        }
    };

    // acc init = bias (z = x-conv + h-conv + bias accumulated in-register)
    float4v acc[8];
#pragma unroll
    for (int j = 0; j < 8; ++j) {
        const int nt = ((j >> 1) << 2) + nh * 2 + (j & 1);
        const float bb = bias[nt * 16 + (lane & 15)];
#pragma unroll
        for (int r = 0; r < 4; ++r) acc[j][r] = bb;
    }

    // prologue: A(0) -> LDS buf0; B(0) -> Bs[0]; A(1) -> reg
    {
        uint4 a0 = gatherA(0);
        stageB(0, 0);
        *(uint4*)((char*)As[0] + awr) = a0;
    }
    uint4 av_w = gatherA(1);
    __syncthreads();    // publishes As[0]; drains B(0) glds

    for (int q = 0; q < TOT; ++q) {
        // issue next-chunk loads FIRST: full chunk body in flight before the barrier
        if (q + 1 < TOT) {
            stageB(q + 1, (q + 1) & 1);
            *(uint4*)((char*)As[(q + 1) & 1] + awr) = av_w;   // A(q+1) reg -> LDS
        }
        if (q + 2 < TOT) av_w = gatherA(q + 2);               // A(q+2) global -> reg

        union { struct { uint2 lo, hi; } u; short8v s; } afr;
        const char* ab = (const char*)As[q & 1] + arow;
        afr.u.lo = *(const uint2*)(ab);
        afr.u.hi = *(const uint2*)(ab + 32);

        const ushort* bs = Bs[q & 1];
        union { uint4 u; short8v s; } bfr[8];
#pragma unroll
        for (int j = 0; j < 8; ++j)
            bfr[j].u = *(const uint4*)(bs + ((j * 64 + lane) << 3));

#pragma unroll
        for (int j = 0; j < 8; ++j)
            acc[j] = __builtin_amdgcn_mfma_f32_16x16x32_bf16(afr.s, bfr[j].s, acc[j], 0, 0, 0);

        __syncthreads();   // single barrier: publishes As/Bs[(q+1)&1], ends reads of [q&1]
    }

    // fused gate epilogue: j=0,1 -> i; 2,3 -> f; 4,5 -> g; 6,7 -> o
#pragma unroll
    for (int jj = 0; jj < 2; ++jj) {
        const int ch = (nh * 2 + jj) * 16 + (lane & 15);   // h-channel 0..63
        float inv = 0.f, mu = 0.f, bet = 0.f;
        if (layer == 0) {
            inv = g0[ch] * rsqrtf(v0[ch] + BN_EPS);
            mu = mn0[ch]; bet = be0[ch];
        }
#pragma unroll
        for (int r = 0; r < 4; ++r) {
            const int p = m0 + wid * 16 + (lane >> 4) * 4 + r;
            const int o = p * 64 + ch;
            float zi = acc[0 + jj][r];
            float zf = acc[2 + jj][r];
            float zg = acc[4 + jj][r];
            float zo = acc[6 + jj][r];
            float cv = hsig(zf) * C[o] + hsig(zi) * tanhf(zg);
            C[o] = cv;
            float h = hsig(zo) * tanhf(cv);
            Hcur[o] = f2bf(h);
            Seq[o] = (layer == 0) ? f2bf((h - mu) * inv + bet) : f2bf(h);
        }
    }
}

// ---------------- pool over all t: BN1(h1) @ denseW -> softmax -> mean ----------------
__global__ __launch_bounds__(256) void pool_all(
    const ushort* __restrict__ H1seq, const float* __restrict__ dW,
    const float* __restrict__ dB,
    const float* __restrict__ gamma, const float* __restrict__ beta,
    const float* __restrict__ mean, const float* __restrict__ var,
    float* __restrict__ out)
{
    __shared__ float accs[NCc];
    int gid = blockIdx.x * 256 + threadIdx.x;   // 512 blocks x 256 = 131072
    int pix = gid & 8191;
    int b = pix >> 10;
    if (threadIdx.x < NCc) accs[threadIdx.x] = 0.f;
    __syncthreads();

    float logit[NCc];
#pragma unroll
    for (int c = 0; c < NCc; ++c) logit[c] = dB[c];
    const ushort* hp = H1seq + (size_t)gid * Fc;
    for (int f0 = 0; f0 < Fc; f0 += 8) {
        uint4 hv = *(const uint4*)(hp + f0);
        union { uint4 u; ushort s[8]; } hu; hu.u = hv;
#pragma unroll
        for (int j = 0; j < 8; ++j) {
            int f = f0 + j;
            float inv = gamma[f] * rsqrtf(var[f] + BN_EPS);
            float v = (bf2f(hu.s[j]) - mean[f]) * inv + beta[f];
#pragma unroll
            for (int c = 0; c < NCc; ++c) logit[c] += v * dW[f * NCc + c];
        }
    }
    float mx = logit[0];
#pragma unroll
    for (int c = 1; c < NCc; ++c) mx = fmaxf(mx, logit[c]);
    float p[NCc]; float s = 0.f;
#pragma unroll
    for (int c = 0; c < NCc; ++c) { p[c] = expf(logit[c] - mx); s += p[c]; }
    float invs = 1.f / s;
#pragma unroll
    for (int c = 0; c < NCc; ++c) atomicAdd(&accs[c], p[c] * invs);
    __syncthreads();
    if (threadIdx.x < NCc)
        atomicAdd(&out[b * NCc + threadIdx.x], accs[threadIdx.x] * (1.0f / 16384.0f));
}

extern "C" void kernel_launch(void* const* d_in, const int* in_sizes, int n_in,
                              void* d_out, int out_size, void* d_ws, size_t ws_size,
                              hipStream_t stream) {
    const float* in    = (const float*)d_in[0];
    const float* l0Wx  = (const float*)d_in[1];
    const float* l0Wh  = (const float*)d_in[2];
    const float* l0b   = (const float*)d_in[3];
    const float* l0g   = (const float*)d_in[4];
    const float* l0be  = (const float*)d_in[5];
    const float* l0m   = (const float*)d_in[6];
    const float* l0v   = (const float*)d_in[7];
    const float* l1Wx  = (const float*)d_in[8];
    const float* l1Wh  = (const float*)d_in[9];
    const float* l1b   = (const float*)d_in[10];
    const float* l1g   = (const float*)d_in[11];
    const float* l1be  = (const float*)d_in[12];
    const float* l1m   = (const float*)d_in[13];
    const float* l1v   = (const float*)d_in[14];
    const float* dW    = (const float*)d_in[15];
    const float* dB    = (const float*)d_in[16];
    float* out = (float*)d_out;

    float* ws   = (float*)d_ws;
    float* c0   = ws;                        // 524,288 f
    float* c1   = c0 + 524288;
    ushort* us  = (ushort*)(c1 + 524288);
    ushort* h0p0 = us;                       // h ping-pong buffers (bf16)
    ushort* h0p1 = h0p0 + 524288;
    ushort* h1p0 = h0p1 + 524288;
    ushort* h1p1 = h1p0 + 524288;
    ushort* xb  = h1p1 + 524288;             // 786,432 us
    ushort* x1  = xb + 786432;               // 16*524,288 us (BN'd layer-0 output)
    ushort* h1s = x1 + 8388608;              // 16*524,288 us (layer-1 h sequence)
    ushort* wf  = h1s + 8388608;             // 458,752 us

    ushort* h0p[2] = { h0p0, h0p1 };
    ushort* h1p[2] = { h1p0, h1p1 };

    prep_x<<<3072, 256, 0, stream>>>(in, xb);
    prep_w<<<1792, 256, 0, stream>>>(l0Wx, l0Wh, l1Wx, l1Wh, wf);
    init_zero<<<2048, 256, 0, stream>>>(c0, c1, h0p0, h1p0, h0p1, h1p1, out);

    // wavefront pipeline: slot t runs layer-0 step t and layer-1 step t-1
    for (int t = 0; t <= Tn; ++t) {
        int t1c = (t > 0) ? (t - 1) : 0;
        step_dual<<<512, 256, 0, stream>>>(
            t, xb,
            wf + FR_L0X, wf + FR_L0H, l0b,
            c0, h0p[t & 1], h0p[(t + 1) & 1], x1,
            l0g, l0be, l0m, l0v,
            wf + FR_L1X, wf + FR_L1H, l1b,
            c1, h1p[t1c & 1], h1p[(t1c + 1) & 1], h1s);
    }
    pool_all<<<512, 256, 0, stream>>>(h1s, dW, dB, l1g, l1be, l1m, l1v, out);
}

// Round 8
// 420.258 us; speedup vs baseline: 1.1334x; 1.1334x over previous
//
#include <hip/hip_runtime.h>
#include <math.h>

typedef __attribute__((ext_vector_type(8))) short short8v;   // 8 bf16 = 4 VGPRs
typedef __attribute__((ext_vector_type(4))) float float4v;   // MFMA acc

constexpr int Bsz = 8, Tn = 16, CINc = 6, Fc = 64, NCc = 10;
constexpr int PIX = 8192;                 // 8*32*32 pixels per timestep
constexpr float BN_EPS = 1e-3f;

// weight-fragment region offsets (in ushort elements)
constexpr int FR_L0X = 0;                 // 2 chunks  (K=54 padded to 64)
constexpr int FR_L0H = 16384;             // 18 chunks (K=576)
constexpr int FR_L1X = 163840;            // 18 chunks
constexpr int FR_L1H = 311296;            // 18 chunks
constexpr int FR_TOTAL = 458752;

__device__ __forceinline__ ushort f2bf(float f) {
    union { float f; unsigned u; } v; v.f = f;
    unsigned r = v.u + 0x7FFFu + ((v.u >> 16) & 1u);   // RNE
    return (ushort)(r >> 16);
}
__device__ __forceinline__ float bf2f(ushort u) {
    union { unsigned u; float f; } v; v.u = ((unsigned)u) << 16; return v.f;
}
__device__ __forceinline__ float hsig(float x) {
    return fminf(fmaxf(0.2f * x + 0.5f, 0.0f), 1.0f);
}

#define GLDS(srcp, dstp) \
    __builtin_amdgcn_global_load_lds((const __attribute__((address_space(1))) void*)(srcp), \
                                     (__attribute__((address_space(3))) void*)(dstp), 16, 0, 0)

// ---------------- prep: x -> bf16 [t][pix][6] ----------------
__global__ __launch_bounds__(256) void prep_x(const float* __restrict__ in,
                                              ushort* __restrict__ xb) {
    int o = blockIdx.x * 256 + threadIdx.x;        // 16*8192*6 = 786432
    if (o >= Tn * PIX * CINc) return;
    int t = o / (PIX * CINc);
    int rem = o - t * (PIX * CINc);
    int pix = rem / CINc, c = rem - pix * CINc;
    int b = pix >> 10, p = pix & 1023;
    xb[o] = f2bf(in[((b * Tn + t) * 1024 + p) * CINc + c]);
}

// ---------------- prep: weights -> grouped B-fragment layout ----------------
// region layout: [kc][nh][j(0..7)][lane(0..63)][e(0..7)]; frag's nt = (j>>1)*4 + nh*2 + (j&1)
// element: k = kc*32 + (lane>>4)*4 + (e&3) + 16*(e>>2); n = nt*16 + (lane&15)
__global__ __launch_bounds__(256) void prep_w(const float* __restrict__ W0x,
                                              const float* __restrict__ W0h,
                                              const float* __restrict__ W1x,
                                              const float* __restrict__ W1h,
                                              ushort* __restrict__ F) {
    int o = blockIdx.x * 256 + threadIdx.x;
    if (o >= FR_TOTAL) return;
    const float* W; int K; int base;
    if (o < FR_L0H)      { W = W0x; K = 54;  base = FR_L0X; }
    else if (o < FR_L1X) { W = W0h; K = 576; base = FR_L0H; }
    else if (o < FR_L1H) { W = W1x; K = 576; base = FR_L1X; }
    else                 { W = W1h; K = 576; base = FR_L1H; }
    int r = o - base;
    int e = r & 7, lane = (r >> 3) & 63, j = (r >> 9) & 7, nh = (r >> 12) & 1, kc = r >> 13;
    int nt = ((j >> 1) << 2) + nh * 2 + (j & 1);
    int k = kc * 32 + ((lane >> 4) * 4) + (e & 3) + 16 * (e >> 2);
    int n = nt * 16 + (lane & 15);
    F[o] = (k < K) ? f2bf(W[k * 256 + n]) : (ushort)0;
}

// ---------------- init ----------------
__global__ __launch_bounds__(256) void init_zero(float* c0, float* c1,
                                                 ushort* h0, ushort* h1,
                                                 ushort* h0b, ushort* h1b, float* out) {
    int i = blockIdx.x * 256 + threadIdx.x;
    if (i < PIX * Fc) { c0[i] = 0.f; c1[i] = 0.f; h0[i] = 0; h1[i] = 0; h0b[i] = 0; h1b[i] = 0; }
    if (i < Bsz * NCc) out[i] = 0.f;
}

// ---------------- 3-stage wavefront step ----------------
// grp0 (blocks   0..255): layer-0 step t    (20 chunks: 2 x + 18 h) -> h0, x1[t]
// grp1 (blocks 256..511): z1[t-1] = conv(x1[t-1],W1x)+b1 (18 chunks) -> z1 frags (fp32)
// grp2 (blocks 512..767): layer-1 step t-2  (18 h-chunks, acc init from z1) -> h1, h1s[t-2]
// Each block: 64 pixels x 128 gate-paired channels (nh half).
__global__ __launch_bounds__(256) void step_tri(
    int t,
    const ushort* __restrict__ Xb,
    const ushort* __restrict__ Bf0X, const ushort* __restrict__ Bf0H,
    const float* __restrict__ b0,
    float* __restrict__ C0, const ushort* __restrict__ H0prev, ushort* __restrict__ H0cur,
    ushort* __restrict__ X1s,
    const float* __restrict__ g0, const float* __restrict__ be0,
    const float* __restrict__ mn0, const float* __restrict__ v0,
    const ushort* __restrict__ Bf1X, const ushort* __restrict__ Bf1H,
    const float* __restrict__ b1, float* __restrict__ Z1,
    float* __restrict__ C1, const ushort* __restrict__ H1prev, ushort* __restrict__ H1cur,
    ushort* __restrict__ H1s)
{
    const int grp = blockIdx.x >> 8;
    int s;
    if (grp == 0)      { s = t;     if (s >= Tn) return; }
    else if (grp == 1) { s = t - 1; if (s < 0 || s >= Tn) return; }
    else               { s = t - 2; if (s < 0 || s >= Tn) return; }

    __shared__ ushort As[64 * 40];        // 64 rows x 32k (+8 pad) = 80B rows
    __shared__ ushort Bs[2][4096];        // double-buffered 8KB B group

    const int tid = threadIdx.x;
    const int wid = tid >> 6, lane = tid & 63;
    const int bid = blockIdx.x & 255;
    const int bm = bid >> 1, nh = bid & 1;
    const int m0 = bm * 64;

    const int p_local = tid >> 2, kq = tid & 3;
    const int p_global = m0 + p_local;
    const int img = p_global >> 10, pp = p_global & 1023;
    const int py = pp >> 5, px = pp & 31;

    const int arow = (wid * 16 + (lane & 15)) * 80 + (lane >> 4) * 8;   // bytes
    const int awr  = p_local * 80 + kq * 16;                            // bytes

    // per-group bindings
    const ushort* __restrict__ Xt   = Xb + s * PIX * CINc;               // grp0 x-path
    const ushort* __restrict__ X1t  = X1s + (size_t)s * (PIX * Fc);      // grp1 input
    float* __restrict__ Zp = Z1 + (((size_t)s * 128 + bm) * 2 + nh) * 8192;  // grp1 out / grp2 in
    const int TOT = (grp == 0) ? 20 : 18;

    auto bptr = [&](int q) -> const ushort* {
        if (grp == 0)
            return (q < 2)  ? Bf0X + ((q * 2 + nh) << 12)
                            : Bf0H + (((q - 2) * 2 + nh) << 12);
        else if (grp == 1)
            return Bf1X + ((q * 2 + nh) << 12);
        else
            return Bf1H + ((q * 2 + nh) << 12);
    };
    auto stageB = [&](int q, int buf) {
        const ushort* g = bptr(q);
        GLDS(g + (tid << 3),         &Bs[buf][(wid) * 512]);
        GLDS(g + ((256 + tid) << 3), &Bs[buf][(4 + wid) * 512]);
    };
    auto gather64 = [&](const ushort* __restrict__ P, int kc) -> uint4 {
        uint4 av = make_uint4(0u, 0u, 0u, 0u);
        int tap = kc >> 1;
        int c0h = ((kc & 1) << 5) + (kq << 3);
        int dy = tap / 3 - 1, dx = tap % 3 - 1;
        int gy = py + dy, gx = px + dx;
        if ((unsigned)gy < 32u && (unsigned)gx < 32u)
            av = *(const uint4*)(P + (((img << 10) + gy * 32 + gx) << 6) + c0h);
        return av;
    };
    auto gatherA = [&](int q) -> uint4 {
        if (grp == 0) {
            if (q < 2) {                         // x path, Ch=6, K=54 pad 64
                union { ushort s[8]; uint4 u; } pk;
#pragma unroll
                for (int j = 0; j < 8; ++j) {
                    int kg = q * 32 + kq * 8 + j;
                    ushort v = 0;
                    if (kg < 54) {
                        int tap = kg / 6, c = kg - tap * 6;
                        int dy = tap / 3 - 1, dx = tap % 3 - 1;
                        int gy = py + dy, gx = px + dx;
                        if ((unsigned)gy < 32u && (unsigned)gx < 32u)
                            v = Xt[((img << 10) + gy * 32 + gx) * 6 + c];
                    }
                    pk.s[j] = v;
                }
                return pk.u;
            }
            return gather64(H0prev, q - 2);
        } else if (grp == 1) {
            return gather64(X1t, q);
        } else {
            return gather64(H1prev, q);
        }
    };

    // acc init: grp0/grp1 = bias (z accumulated in-register); grp2 = z1 fragments
    float4v acc[8];
    if (grp == 2) {
#pragma unroll
        for (int j = 0; j < 8; ++j)
            acc[j] = *(const float4v*)(Zp + (((j * 4 + wid) * 64 + lane) << 2));
    } else {
        const float* __restrict__ bias = (grp == 0) ? b0 : b1;
#pragma unroll
        for (int j = 0; j < 8; ++j) {
            const int nt = ((j >> 1) << 2) + nh * 2 + (j & 1);
            const float bb = bias[nt * 16 + (lane & 15)];
#pragma unroll
            for (int r = 0; r < 4; ++r) acc[j][r] = bb;
        }
    }

    // prologue (round-6 proven body: two barriers per chunk)
    uint4 av = gatherA(0);
    stageB(0, 0);

    for (int q = 0; q < TOT; ++q) {
        __syncthreads();    // drains glds of B(q); prior iter's LDS reads done
        *(uint4*)((char*)As + awr) = av;
        __syncthreads();    // publish As

        union { struct { uint2 lo, hi; } u; short8v s; } afr;
        afr.u.lo = *(const uint2*)((const char*)As + arow);
        afr.u.hi = *(const uint2*)((const char*)As + arow + 32);

        const ushort* bs = Bs[q & 1];
        union { uint4 u; short8v s; } bfr[8];
#pragma unroll
        for (int j = 0; j < 8; ++j)
            bfr[j].u = *(const uint4*)(bs + ((j * 64 + lane) << 3));

        if (q + 1 < TOT) {                      // prefetch during MFMA region
            stageB(q + 1, (q + 1) & 1);
            av = gatherA(q + 1);
        }

#pragma unroll
        for (int j = 0; j < 8; ++j)
            acc[j] = __builtin_amdgcn_mfma_f32_16x16x32_bf16(afr.s, bfr[j].s, acc[j], 0, 0, 0);
    }

    // ---------------- epilogues ----------------
    if (grp == 1) {                             // store z1 fragments (fp32, coalesced)
#pragma unroll
        for (int j = 0; j < 8; ++j) {
            float4 o;
            o.x = acc[j][0]; o.y = acc[j][1]; o.z = acc[j][2]; o.w = acc[j][3];
            *(float4*)(Zp + (((j * 4 + wid) * 64 + lane) << 2)) = o;
        }
        return;
    }

    // LSTM gate epilogue: j=0,1 -> i; 2,3 -> f; 4,5 -> g; 6,7 -> o
    float* __restrict__ C  = (grp == 0) ? C0 : C1;
    ushort* __restrict__ Hc = (grp == 0) ? H0cur : H1cur;
    ushort* __restrict__ Seq = (grp == 0) ? (X1s + (size_t)s * (PIX * Fc))
                                          : (H1s + (size_t)s * (PIX * Fc));
#pragma unroll
    for (int jj = 0; jj < 2; ++jj) {
        const int ch = (nh * 2 + jj) * 16 + (lane & 15);   // h-channel 0..63
        float inv = 0.f, mu = 0.f, bet = 0.f;
        if (grp == 0) {
            inv = g0[ch] * rsqrtf(v0[ch] + BN_EPS);
            mu = mn0[ch]; bet = be0[ch];
        }
#pragma unroll
        for (int r = 0; r < 4; ++r) {
            const int p = m0 + wid * 16 + (lane >> 4) * 4 + r;
            const int o = p * 64 + ch;
            float zi = acc[0 + jj][r];
            float zf = acc[2 + jj][r];
            float zg = acc[4 + jj][r];
            float zo = acc[6 + jj][r];
            float cv = hsig(zf) * C[o] + hsig(zi) * tanhf(zg);
            C[o] = cv;
            float h = hsig(zo) * tanhf(cv);
            Hc[o] = f2bf(h);
            Seq[o] = (grp == 0) ? f2bf((h - mu) * inv + bet) : f2bf(h);
        }
    }
}

// ---------------- pool over all t: BN1(h1) @ denseW -> softmax -> mean ----------------
__global__ __launch_bounds__(256) void pool_all(
    const ushort* __restrict__ H1seq, const float* __restrict__ dW,
    const float* __restrict__ dB,
    const float* __restrict__ gamma, const float* __restrict__ beta,
    const float* __restrict__ mean, const float* __restrict__ var,
    float* __restrict__ out)
{
    __shared__ float accs[NCc];
    int gid = blockIdx.x * 256 + threadIdx.x;   // 512 blocks x 256 = 131072
    int pix = gid & 8191;
    int b = pix >> 10;
    if (threadIdx.x < NCc) accs[threadIdx.x] = 0.f;
    __syncthreads();

    float logit[NCc];
#pragma unroll
    for (int c = 0; c < NCc; ++c) logit[c] = dB[c];
    const ushort* hp = H1seq + (size_t)gid * Fc;
    for (int f0 = 0; f0 < Fc; f0 += 8) {
        uint4 hv = *(const uint4*)(hp + f0);
        union { uint4 u; ushort s[8]; } hu; hu.u = hv;
#pragma unroll
        for (int j = 0; j < 8; ++j) {
            int f = f0 + j;
            float inv = gamma[f] * rsqrtf(var[f] + BN_EPS);
            float v = (bf2f(hu.s[j]) - mean[f]) * inv + beta[f];
#pragma unroll
            for (int c = 0; c < NCc; ++c) logit[c] += v * dW[f * NCc + c];
        }
    }
    float mx = logit[0];
#pragma unroll
    for (int c = 1; c < NCc; ++c) mx = fmaxf(mx, logit[c]);
    float p[NCc]; float s = 0.f;
#pragma unroll
    for (int c = 0; c < NCc; ++c) { p[c] = expf(logit[c] - mx); s += p[c]; }
    float invs = 1.f / s;
#pragma unroll
    for (int c = 0; c < NCc; ++c) atomicAdd(&accs[c], p[c] * invs);
    __syncthreads();
    if (threadIdx.x < NCc)
        atomicAdd(&out[b * NCc + threadIdx.x], accs[threadIdx.x] * (1.0f / 16384.0f));
}

extern "C" void kernel_launch(void* const* d_in, const int* in_sizes, int n_in,
                              void* d_out, int out_size, void* d_ws, size_t ws_size,
                              hipStream_t stream) {
    const float* in    = (const float*)d_in[0];
    const float* l0Wx  = (const float*)d_in[1];
    const float* l0Wh  = (const float*)d_in[2];
    const float* l0b   = (const float*)d_in[3];
    const float* l0g   = (const float*)d_in[4];
    const float* l0be  = (const float*)d_in[5];
    const float* l0m   = (const float*)d_in[6];
    const float* l0v   = (const float*)d_in[7];
    const float* l1Wx  = (const float*)d_in[8];
    const float* l1Wh  = (const float*)d_in[9];
    const float* l1b   = (const float*)d_in[10];
    const float* l1g   = (const float*)d_in[11];
    const float* l1be  = (const float*)d_in[12];
    const float* l1m   = (const float*)d_in[13];
    const float* l1v   = (const float*)d_in[14];
    const float* dW    = (const float*)d_in[15];
    const float* dB    = (const float*)d_in[16];
    float* out = (float*)d_out;

    float* ws   = (float*)d_ws;
    float* c0   = ws;                        // 524,288 f
    float* c1   = c0 + 524288;
    float* z1   = c1 + 524288;               // 33,554,432 f (134 MB) z1 fragments
    ushort* us  = (ushort*)(z1 + 33554432);
    ushort* h0p0 = us;                       // h ping-pong buffers (bf16)
    ushort* h0p1 = h0p0 + 524288;
    ushort* h1p0 = h0p1 + 524288;
    ushort* h1p1 = h1p0 + 524288;
    ushort* xb  = h1p1 + 524288;             // 786,432 us
    ushort* x1  = xb + 786432;               // 16*524,288 us (BN'd layer-0 output)
    ushort* h1s = x1 + 8388608;              // 16*524,288 us (layer-1 h sequence)
    ushort* wf  = h1s + 8388608;             // 458,752 us

    ushort* h0p[2] = { h0p0, h0p1 };
    ushort* h1p[2] = { h1p0, h1p1 };

    prep_x<<<3072, 256, 0, stream>>>(in, xb);
    prep_w<<<1792, 256, 0, stream>>>(l0Wx, l0Wh, l1Wx, l1Wh, wf);
    init_zero<<<2048, 256, 0, stream>>>(c0, c1, h0p0, h1p0, h0p1, h1p1, out);

    // 3-stage wavefront: slot t = { L0 step t, z1[t-1], L1 step t-2 }
    for (int t = 0; t < Tn + 2; ++t) {
        step_tri<<<768, 256, 0, stream>>>(
            t, xb,
            wf + FR_L0X, wf + FR_L0H, l0b,
            c0, h0p[t & 1], h0p[(t + 1) & 1], x1,
            l0g, l0be, l0m, l0v,
            wf + FR_L1X, wf + FR_L1H, l1b, z1,
            c1, h1p[t & 1], h1p[(t + 1) & 1], h1s);
    }
    pool_all<<<512, 256, 0, stream>>>(h1s, dW, dB, l1g, l1be, l1m, l1v, out);
}

// Round 9
// 364.395 us; speedup vs baseline: 1.3072x; 1.1533x over previous
//
#include <hip/hip_runtime.h>
#include <math.h>

typedef __attribute__((ext_vector_type(8))) short short8v;   // 8 bf16 = 4 VGPRs
typedef __attribute__((ext_vector_type(4))) float float4v;   // MFMA acc

constexpr int Bsz = 8, Tn = 16, CINc = 6, Fc = 64, NCc = 10;
constexpr int PIX = 8192;                 // 8*32*32 pixels per timestep
constexpr float BN_EPS = 1e-3f;

// weight-fragment region offsets (in ushort elements)
constexpr int FR_L0X = 0;                 // 2 chunks  (K=54 padded to 64)
constexpr int FR_L0H = 16384;             // 18 chunks (K=576)
constexpr int FR_L1X = 163840;            // 18 chunks
constexpr int FR_L1H = 311296;            // 18 chunks
constexpr int FR_TOTAL = 458752;

__device__ __forceinline__ ushort f2bf(float f) {
    union { float f; unsigned u; } v; v.f = f;
    unsigned r = v.u + 0x7FFFu + ((v.u >> 16) & 1u);   // RNE
    return (ushort)(r >> 16);
}
__device__ __forceinline__ float bf2f(ushort u) {
    union { unsigned u; float f; } v; v.u = ((unsigned)u) << 16; return v.f;
}
__device__ __forceinline__ float hsig(float x) {
    return fminf(fmaxf(0.2f * x + 0.5f, 0.0f), 1.0f);
}

#define GLDS(srcp, dstp) \
    __builtin_amdgcn_global_load_lds((const __attribute__((address_space(1))) void*)(srcp), \
                                     (__attribute__((address_space(3))) void*)(dstp), 16, 0, 0)

// ---------------- prep: x -> bf16 [t][pix][6] ----------------
__global__ __launch_bounds__(256) void prep_x(const float* __restrict__ in,
                                              ushort* __restrict__ xb) {
    int o = blockIdx.x * 256 + threadIdx.x;        // 16*8192*6 = 786432
    if (o >= Tn * PIX * CINc) return;
    int t = o / (PIX * CINc);
    int rem = o - t * (PIX * CINc);
    int pix = rem / CINc, c = rem - pix * CINc;
    int b = pix >> 10, p = pix & 1023;
    xb[o] = f2bf(in[((b * Tn + t) * 1024 + p) * CINc + c]);
}

// ---------------- prep: weights -> grouped B-fragment layout ----------------
// region layout: [kc][nh][j(0..7)][lane(0..63)][e(0..7)]; frag's nt = (j>>1)*4 + nh*2 + (j&1)
// element: k = kc*32 + (lane>>4)*4 + (e&3) + 16*(e>>2); n = nt*16 + (lane&15)
__global__ __launch_bounds__(256) void prep_w(const float* __restrict__ W0x,
                                              const float* __restrict__ W0h,
                                              const float* __restrict__ W1x,
                                              const float* __restrict__ W1h,
                                              ushort* __restrict__ F) {
    int o = blockIdx.x * 256 + threadIdx.x;
    if (o >= FR_TOTAL) return;
    const float* W; int K; int base;
    if (o < FR_L0H)      { W = W0x; K = 54;  base = FR_L0X; }
    else if (o < FR_L1X) { W = W0h; K = 576; base = FR_L0H; }
    else if (o < FR_L1H) { W = W1x; K = 576; base = FR_L1X; }
    else                 { W = W1h; K = 576; base = FR_L1H; }
    int r = o - base;
    int e = r & 7, lane = (r >> 3) & 63, j = (r >> 9) & 7, nh = (r >> 12) & 1, kc = r >> 13;
    int nt = ((j >> 1) << 2) + nh * 2 + (j & 1);
    int k = kc * 32 + ((lane >> 4) * 4) + (e & 3) + 16 * (e >> 2);
    int n = nt * 16 + (lane & 15);
    F[o] = (k < K) ? f2bf(W[k * 256 + n]) : (ushort)0;
}

// ---------------- prep: fold BN1 into dense layer ----------------
// dWf[f][c] = inv_f * dW[f][c];  dBf[c] = dB[c] + sum_f (beta_f - mean_f*inv_f) * dW[f][c]
__global__ __launch_bounds__(640) void prep_dense(
    const float* __restrict__ dW, const float* __restrict__ dB,
    const float* __restrict__ g, const float* __restrict__ be,
    const float* __restrict__ mn, const float* __restrict__ vr,
    float* __restrict__ dWf, float* __restrict__ dBf)
{
    __shared__ float sc[64], sh[64];
    int tid = threadIdx.x;
    if (tid < 64) {
        float s = g[tid] * rsqrtf(vr[tid] + BN_EPS);
        sc[tid] = s; sh[tid] = be[tid] - mn[tid] * s;
    }
    __syncthreads();
    if (tid < 640) { int f = tid / 10; dWf[tid] = sc[f] * dW[tid]; }
    if (tid < NCc) {
        float a = dB[tid];
        for (int f = 0; f < 64; ++f) a += sh[f] * dW[f * 10 + tid];
        dBf[tid] = a;
    }
}

// ---------------- init ----------------
__global__ __launch_bounds__(256) void init_zero(float* c0, float* c1,
                                                 ushort* h0, ushort* h1,
                                                 ushort* h0b, ushort* h1b, float* out) {
    int i = blockIdx.x * 256 + threadIdx.x;
    if (i < PIX * Fc) { c0[i] = 0.f; c1[i] = 0.f; h0[i] = 0; h1[i] = 0; h0b[i] = 0; h1b[i] = 0; }
    if (i < Bsz * NCc) out[i] = 0.f;
}

// ---------------- 3-stage wavefront step, BK=64 (one 3x3 tap per chunk) ----------------
// grp0 (blocks   0..255): layer-0 step t    (10 chunks: 1 x + 9 taps) -> h0, x1[t]
// grp1 (blocks 256..511): z1[t-1] = conv(x1[t-1],W1x)+b1 (9 taps) -> z1 frags (fp32)
// grp2 (blocks 512..767): layer-1 step t-2  (9 h-taps, acc init from z1) -> h1, h1s[t-2]
__global__ __launch_bounds__(256, 3) void step_tri(
    int t,
    const ushort* __restrict__ Xb,
    const ushort* __restrict__ Bf0X, const ushort* __restrict__ Bf0H,
    const float* __restrict__ b0,
    float* __restrict__ C0, const ushort* __restrict__ H0prev, ushort* __restrict__ H0cur,
    ushort* __restrict__ X1s,
    const float* __restrict__ g0, const float* __restrict__ be0,
    const float* __restrict__ mn0, const float* __restrict__ v0,
    const ushort* __restrict__ Bf1X, const ushort* __restrict__ Bf1H,
    const float* __restrict__ b1, float* __restrict__ Z1,
    float* __restrict__ C1, const ushort* __restrict__ H1prev, ushort* __restrict__ H1cur,
    ushort* __restrict__ H1s)
{
    const int grp = blockIdx.x >> 8;
    int s;
    if (grp == 0)      { s = t;     if (s >= Tn) return; }
    else if (grp == 1) { s = t - 1; if (s < 0 || s >= Tn) return; }
    else               { s = t - 2; if (s < 0 || s >= Tn) return; }

    __shared__ ushort As[64 * 72];        // 64 rows x 64k bf16 + 16B pad = 144B rows
    __shared__ ushort Bs[2][8192];        // dbuf: 16KB B pair (2 sub-chunks of 8KB)

    const int tid = threadIdx.x;
    const int wid = tid >> 6, lane = tid & 63;
    const int bid = blockIdx.x & 255;
    const int bm = bid >> 1, nh = bid & 1;
    const int m0 = bm * 64;

    const int p_local = tid >> 2, kq = tid & 3;
    const int p_global = m0 + p_local;
    const int img = p_global >> 10, pp = p_global & 1023;
    const int py = pp >> 5, px = pp & 31;

    const int arow = (wid * 16 + (lane & 15)) * 144 + (lane >> 4) * 8;   // bytes
    const int awr  = p_local * 144 + kq * 16;                            // bytes

    // per-group bindings
    const ushort* __restrict__ Xt   = Xb + s * PIX * CINc;               // grp0 x-path
    const ushort* __restrict__ X1t  = X1s + (size_t)s * (PIX * Fc);      // grp1 input
    float* __restrict__ Zp = Z1 + (((size_t)s * 128 + bm) * 2 + nh) * 8192;  // grp1 out / grp2 in
    const int TOT = (grp == 0) ? 10 : 9;

    auto stageB = [&](int q, int buf) {
        const ushort *g0p, *g1p;
        if (grp == 0) {
            if (q == 0) { g0p = Bf0X + (nh << 12); g1p = Bf0X + ((2 + nh) << 12); }
            else { int tp = q - 1;
                   g0p = Bf0H + ((4 * tp + nh) << 12);
                   g1p = Bf0H + ((4 * tp + 2 + nh) << 12); }
        } else if (grp == 1) {
            g0p = Bf1X + ((4 * q + nh) << 12);
            g1p = Bf1X + ((4 * q + 2 + nh) << 12);
        } else {
            g0p = Bf1H + ((4 * q + nh) << 12);
            g1p = Bf1H + ((4 * q + 2 + nh) << 12);
        }
        ushort* d = &Bs[buf][0];
        GLDS(g0p + (tid << 3),         d + wid * 512);
        GLDS(g0p + ((256 + tid) << 3), d + 2048 + wid * 512);
        GLDS(g1p + (tid << 3),         d + 4096 + wid * 512);
        GLDS(g1p + ((256 + tid) << 3), d + 4096 + 2048 + wid * 512);
    };
    auto gather64 = [&](const ushort* __restrict__ P, int tap, uint4& a0, uint4& a1) {
        a0 = make_uint4(0u, 0u, 0u, 0u); a1 = a0;
        int dy = tap / 3 - 1, dx = tap % 3 - 1;
        int gy = py + dy, gx = px + dx;
        if ((unsigned)gy < 32u && (unsigned)gx < 32u) {
            const ushort* bp = P + (((img << 10) + gy * 32 + gx) << 6) + (kq << 3);
            a0 = *(const uint4*)bp;
            a1 = *(const uint4*)(bp + 32);
        }
    };
    auto gatherA = [&](int q, uint4& a0, uint4& a1) {
        if (grp == 0) {
            if (q == 0) {                        // x path, Ch=6, K=54 pad 64
                union { ushort s[8]; uint4 u; } p0, p1;
#pragma unroll
                for (int j = 0; j < 8; ++j) {
                    // quarter kq: kg = kq*8+j (always < 54)
                    {
                        int kg = kq * 8 + j;
                        int tap = kg / 6, c = kg - tap * 6;
                        int dy = tap / 3 - 1, dx = tap % 3 - 1;
                        int gy = py + dy, gx = px + dx;
                        ushort v = 0;
                        if ((unsigned)gy < 32u && (unsigned)gx < 32u)
                            v = Xt[((img << 10) + gy * 32 + gx) * 6 + c];
                        p0.s[j] = v;
                    }
                    {
                        int kg = 32 + kq * 8 + j;
                        ushort v = 0;
                        if (kg < 54) {
                            int tap = kg / 6, c = kg - tap * 6;
                            int dy = tap / 3 - 1, dx = tap % 3 - 1;
                            int gy = py + dy, gx = px + dx;
                            if ((unsigned)gy < 32u && (unsigned)gx < 32u)
                                v = Xt[((img << 10) + gy * 32 + gx) * 6 + c];
                        }
                        p1.s[j] = v;
                    }
                }
                a0 = p0.u; a1 = p1.u;
                return;
            }
            gather64(H0prev, q - 1, a0, a1);
        } else if (grp == 1) {
            gather64(X1t, q, a0, a1);
        } else {
            gather64(H1prev, q, a0, a1);
        }
    };

    // acc init: grp0/grp1 = bias; grp2 = z1 fragments
    float4v acc[8];
    if (grp == 2) {
#pragma unroll
        for (int j = 0; j < 8; ++j)
            acc[j] = *(const float4v*)(Zp + (((j * 4 + wid) * 64 + lane) << 2));
    } else {
        const float* __restrict__ bias = (grp == 0) ? b0 : b1;
#pragma unroll
        for (int j = 0; j < 8; ++j) {
            const int nt = ((j >> 1) << 2) + nh * 2 + (j & 1);
            const float bb = bias[nt * 16 + (lane & 15)];
#pragma unroll
            for (int r = 0; r < 4; ++r) acc[j][r] = bb;
        }
    }

    // prologue (round-6 proven body: two barriers per chunk)
    uint4 av0, av1;
    gatherA(0, av0, av1);
    stageB(0, 0);

    for (int q = 0; q < TOT; ++q) {
        __syncthreads();    // drains glds of B(q) + A loads; prior iter's LDS reads done
        *(uint4*)((char*)As + awr) = av0;
        *(uint4*)((char*)As + awr + 64) = av1;
        __syncthreads();    // publish As

        union { struct { uint2 lo, hi; } u; short8v s; } af0, af1;
        const char* ab = (const char*)As + arow;
        af0.u.lo = *(const uint2*)(ab);
        af0.u.hi = *(const uint2*)(ab + 32);
        af1.u.lo = *(const uint2*)(ab + 64);
        af1.u.hi = *(const uint2*)(ab + 96);

        const ushort* bs = &Bs[q & 1][0];
        union { uint4 u; short8v s; } b0r[8], b1r[8];
#pragma unroll
        for (int j = 0; j < 8; ++j) {
            b0r[j].u = *(const uint4*)(bs + ((j * 64 + lane) << 3));
            b1r[j].u = *(const uint4*)(bs + 4096 + ((j * 64 + lane) << 3));
        }

        if (q + 1 < TOT) {                      // prefetch during MFMA region
            stageB(q + 1, (q + 1) & 1);
            gatherA(q + 1, av0, av1);
        }

#pragma unroll
        for (int j = 0; j < 8; ++j)
            acc[j] = __builtin_amdgcn_mfma_f32_16x16x32_bf16(af0.s, b0r[j].s, acc[j], 0, 0, 0);
#pragma unroll
        for (int j = 0; j < 8; ++j)
            acc[j] = __builtin_amdgcn_mfma_f32_16x16x32_bf16(af1.s, b1r[j].s, acc[j], 0, 0, 0);
    }

    // ---------------- epilogues ----------------
    if (grp == 1) {                             // store z1 fragments (fp32, coalesced)
#pragma unroll
        for (int j = 0; j < 8; ++j) {
            float4 o;
            o.x = acc[j][0]; o.y = acc[j][1]; o.z = acc[j][2]; o.w = acc[j][3];
            *(float4*)(Zp + (((j * 4 + wid) * 64 + lane) << 2)) = o;
        }
        return;
    }

    // LSTM gate epilogue: j=0,1 -> i; 2,3 -> f; 4,5 -> g; 6,7 -> o
    float* __restrict__ C  = (grp == 0) ? C0 : C1;
    ushort* __restrict__ Hc = (grp == 0) ? H0cur : H1cur;
    ushort* __restrict__ Seq = (grp == 0) ? (X1s + (size_t)s * (PIX * Fc))
                                          : (H1s + (size_t)s * (PIX * Fc));
#pragma unroll
    for (int jj = 0; jj < 2; ++jj) {
        const int ch = (nh * 2 + jj) * 16 + (lane & 15);   // h-channel 0..63
        float inv = 0.f, mu = 0.f, bet = 0.f;
        if (grp == 0) {
            inv = g0[ch] * rsqrtf(v0[ch] + BN_EPS);
            mu = mn0[ch]; bet = be0[ch];
        }
#pragma unroll
        for (int r = 0; r < 4; ++r) {
            const int p = m0 + wid * 16 + (lane >> 4) * 4 + r;
            const int o = p * 64 + ch;
            float zi = acc[0 + jj][r];
            float zf = acc[2 + jj][r];
            float zg = acc[4 + jj][r];
            float zo = acc[6 + jj][r];
            float cv = hsig(zf) * C[o] + hsig(zi) * tanhf(zg);
            C[o] = cv;
            float h = hsig(zo) * tanhf(cv);
            Hc[o] = f2bf(h);
            Seq[o] = (grp == 0) ? f2bf((h - mu) * inv + bet) : f2bf(h);
        }
    }
}

// ---------------- pool over all t: h1 @ dWf (BN folded) -> softmax -> mean ----------------
__global__ __launch_bounds__(256) void pool_all(
    const ushort* __restrict__ H1seq, const float* __restrict__ dWf,
    const float* __restrict__ dBf, float* __restrict__ out)
{
    __shared__ float wlds[640];
    __shared__ float accs[NCc];
    const int tid = threadIdx.x;
    for (int i = tid; i < 640; i += 256) wlds[i] = dWf[i];
    if (tid < NCc) accs[tid] = 0.f;
    __syncthreads();

    const int gid = blockIdx.x * 256 + tid;   // 512 blocks x 256 = 131072
    const int b = (gid & 8191) >> 10;          // uniform per block

    float logit[NCc];
#pragma unroll
    for (int c = 0; c < NCc; ++c) logit[c] = dBf[c];
    const ushort* hp = H1seq + (size_t)gid * Fc;
#pragma unroll
    for (int f0 = 0; f0 < 8; ++f0) {
        union { uint4 u; ushort s[8]; } hu;
        hu.u = *(const uint4*)(hp + f0 * 8);
#pragma unroll
        for (int j = 0; j < 8; ++j) {
            float v = bf2f(hu.s[j]);
            const float* w = &wlds[(f0 * 8 + j) * 10];
#pragma unroll
            for (int c = 0; c < NCc; ++c) logit[c] += v * w[c];
        }
    }
    float mx = logit[0];
#pragma unroll
    for (int c = 1; c < NCc; ++c) mx = fmaxf(mx, logit[c]);
    float p[NCc]; float ssum = 0.f;
#pragma unroll
    for (int c = 0; c < NCc; ++c) { p[c] = expf(logit[c] - mx); ssum += p[c]; }
    float invs = 1.f / ssum;

    // wave butterfly reduction per class, then one LDS atomic per wave
#pragma unroll
    for (int c = 0; c < NCc; ++c) {
        float v = p[c] * invs;
        v += __shfl_xor(v, 1);
        v += __shfl_xor(v, 2);
        v += __shfl_xor(v, 4);
        v += __shfl_xor(v, 8);
        v += __shfl_xor(v, 16);
        v += __shfl_xor(v, 32);
        if ((tid & 63) == 0) atomicAdd(&accs[c], v);
    }
    __syncthreads();
    if (tid < NCc)
        atomicAdd(&out[b * NCc + tid], accs[tid] * (1.0f / 16384.0f));
}

extern "C" void kernel_launch(void* const* d_in, const int* in_sizes, int n_in,
                              void* d_out, int out_size, void* d_ws, size_t ws_size,
                              hipStream_t stream) {
    const float* in    = (const float*)d_in[0];
    const float* l0Wx  = (const float*)d_in[1];
    const float* l0Wh  = (const float*)d_in[2];
    const float* l0b   = (const float*)d_in[3];
    const float* l0g   = (const float*)d_in[4];
    const float* l0be  = (const float*)d_in[5];
    const float* l0m   = (const float*)d_in[6];
    const float* l0v   = (const float*)d_in[7];
    const float* l1Wx  = (const float*)d_in[8];
    const float* l1Wh  = (const float*)d_in[9];
    const float* l1b   = (const float*)d_in[10];
    const float* l1g   = (const float*)d_in[11];
    const float* l1be  = (const float*)d_in[12];
    const float* l1m   = (const float*)d_in[13];
    const float* l1v   = (const float*)d_in[14];
    const float* dW    = (const float*)d_in[15];
    const float* dB    = (const float*)d_in[16];
    float* out = (float*)d_out;

    float* ws   = (float*)d_ws;
    float* c0   = ws;                        // 524,288 f
    float* c1   = c0 + 524288;
    float* z1   = c1 + 524288;               // 33,554,432 f (134 MB) z1 fragments
    ushort* us  = (ushort*)(z1 + 33554432);
    ushort* h0p0 = us;                       // h ping-pong buffers (bf16)
    ushort* h0p1 = h0p0 + 524288;
    ushort* h1p0 = h0p1 + 524288;
    ushort* h1p1 = h1p0 + 524288;
    ushort* xb  = h1p1 + 524288;             // 786,432 us
    ushort* x1  = xb + 786432;               // 16*524,288 us (BN'd layer-0 output)
    ushort* h1s = x1 + 8388608;              // 16*524,288 us (layer-1 h sequence)
    ushort* wf  = h1s + 8388608;             // 458,752 us
    float* dWf  = (float*)(wf + 458752);     // 640 f (BN-folded dense W)
    float* dBf  = dWf + 640;                 // 10 f

    ushort* h0p[2] = { h0p0, h0p1 };
    ushort* h1p[2] = { h1p0, h1p1 };

    prep_x<<<3072, 256, 0, stream>>>(in, xb);
    prep_w<<<1792, 256, 0, stream>>>(l0Wx, l0Wh, l1Wx, l1Wh, wf);
    prep_dense<<<1, 640, 0, stream>>>(dW, dB, l1g, l1be, l1m, l1v, dWf, dBf);
    init_zero<<<2048, 256, 0, stream>>>(c0, c1, h0p0, h1p0, h0p1, h1p1, out);

    // 3-stage wavefront: slot t = { L0 step t, z1[t-1], L1 step t-2 }
    for (int t = 0; t < Tn + 2; ++t) {
        step_tri<<<768, 256, 0, stream>>>(
            t, xb,
            wf + FR_L0X, wf + FR_L0H, l0b,
            c0, h0p[t & 1], h0p[(t + 1) & 1], x1,
            l0g, l0be, l0m, l0v,
            wf + FR_L1X, wf + FR_L1H, l1b, z1,
            c1, h1p[t & 1], h1p[(t + 1) & 1], h1s);
    }
    pool_all<<<512, 256, 0, stream>>>(h1s, dWf, dBf, out);
}